// Round 5
// baseline (308.581 us; speedup 1.0000x reference)
//
#include <hip/hip_runtime.h>

#define DIM 1024
#define BATCH 4
#define SEQ 4096
#define NH 16
#define HD 64
#define KP 256

typedef float f32x4 __attribute__((ext_vector_type(4)));
typedef _Float16 half8 __attribute__((ext_vector_type(8)));
typedef int i32x4 __attribute__((ext_vector_type(4)));

__device__ __forceinline__ void gll16(const void* g, void* l) {
  __builtin_amdgcn_global_load_lds(
      (const __attribute__((address_space(1))) void*)g,
      (__attribute__((address_space(3))) void*)l, 16, 0, 0);
}

__device__ __forceinline__ unsigned lds_addr(const void* p) {
  return (unsigned)(size_t)(const __attribute__((address_space(3))) void*)p;
}

#define DSR128(dst, base, imm)                                               \
  asm volatile("ds_read_b128 %0, %1 offset:" #imm : "=&v"(dst) : "v"(base))

#define BARR __builtin_amdgcn_s_barrier()
#define LGKM0                                                                \
  do {                                                                       \
    asm volatile("s_waitcnt lgkmcnt(0)" ::: "memory");                       \
    __builtin_amdgcn_sched_barrier(0);                                       \
  } while (0)
#define VMC(n) asm volatile("s_waitcnt vmcnt(" #n ")" ::: "memory")

// DPP row_ror:n within 16-lane rows. ctrl = 0x120|n.
#define DPPF(v, ctrl)                                                        \
  __builtin_bit_cast(float, __builtin_amdgcn_mov_dpp(                        \
                                __builtin_bit_cast(int, v), ctrl, 0xF, 0xF, true))

// ---- fp32 -> fp16 elementwise convert, 8 elems/thread ----
__global__ void k_cvt(const float* __restrict__ s, _Float16* __restrict__ d) {
  int i = (blockIdx.x * 256 + threadIdx.x) * 8;
  f32x4 a = *(const f32x4*)(s + i);
  f32x4 b = *(const f32x4*)(s + i + 4);
  half8 h;
  h[0] = a[0]; h[1] = a[1]; h[2] = a[2]; h[3] = a[3];
  h[4] = b[0]; h[5] = b[1]; h[6] = b[2]; h[7] = b[3];
  *(half8*)(d + i) = h;
}

// Wq and Wo converts merged: grid 1024 blocks
__global__ void k_cvtw(const float* __restrict__ Wq, const float* __restrict__ Wo,
                       _Float16* __restrict__ Wq_h, _Float16* __restrict__ Wo_h) {
  int bb = blockIdx.x;
  const float* s = (bb < 512) ? Wq : Wo;
  _Float16* d = (bb < 512) ? Wq_h : Wo_h;
  int i = ((bb & 511) * 256 + threadIdx.x) * 8;
  f32x4 a = *(const f32x4*)(s + i);
  f32x4 b = *(const f32x4*)(s + i + 4);
  half8 h;
  h[0] = a[0]; h[1] = a[1]; h[2] = a[2]; h[3] = a[3];
  h[4] = b[0]; h[5] = b[1]; h[6] = b[2]; h[7] = b[3];
  *(half8*)(d + i) = h;
}

// misc small work merged: grid 88 blocks
__global__ void k_misc(const float* __restrict__ E, const float* __restrict__ F,
                       _Float16* __restrict__ E_h, _Float16* __restrict__ Ft,
                       float* __restrict__ xsum) {
  int bb = blockIdx.x;
  if (bb < 16) {
    xsum[bb * 256 + threadIdx.x] = 0.f;
  } else if (bb < 24) {
    int i = ((bb - 16) * 256 + threadIdx.x) * 8;
    f32x4 a = *(const f32x4*)(E + i);
    f32x4 b = *(const f32x4*)(E + i + 4);
    half8 h;
    h[0] = a[0]; h[1] = a[1]; h[2] = a[2]; h[3] = a[3];
    h[4] = b[0]; h[5] = b[1]; h[6] = b[2]; h[7] = b[3];
    *(half8*)(E_h + i) = h;
  } else {
    int i = (bb - 24) * 256 + threadIdx.x;  // 16384
    int k = i >> 6, d = i & 63;
    Ft[d * KP + (k & 15) * 16 + (k >> 4)] = (_Float16)F[i];
  }
}

// xsum[b,c] = sum_n x[b,n,c]; reads fp16 x_h; grid (4,B,32)
__global__ void k_xsum(const _Float16* __restrict__ xh, float* __restrict__ xs) {
  int c = blockIdx.x * 256 + threadIdx.x;
  int b = blockIdx.y;
  int n0 = blockIdx.z * 128;
  const _Float16* p = xh + (size_t)(b * SEQ + n0) * DIM + c;
  float s = 0.f;
  #pragma unroll 8
  for (int i = 0; i < 128; i++) s += (float)p[i * DIM];
  atomicAdd(&xs[b * DIM + c], s);
}

// Sk[b,c] = xsum[b,:]@Wk[c,:], Sv likewise. One wave per output dot.
__global__ void k_sksv(const float* __restrict__ xs, const float* __restrict__ Wk,
                       const float* __restrict__ Wv, float* __restrict__ Sk,
                       float* __restrict__ Sv) {
  int idx = blockIdx.x * 4 + (threadIdx.x >> 6);
  int lane = threadIdx.x & 63;
  int kv = idx >> 12;
  int rem = idx & 4095;
  int b = rem >> 10, c = rem & 1023;
  const float* W = (kv ? Wv : Wk) + c * DIM;
  const float* xp = xs + b * DIM;
  float a = 0.f;
  #pragma unroll
  for (int i = 0; i < 16; i++) a += xp[lane + i * 64] * W[lane + i * 64];
  for (int off = 32; off; off >>= 1) a += __shfl_down(a, off);
  if (lane == 0) (kv ? Sv : Sk)[rem] = a;
}

// ---- fp16 MFMA GEMM, round 7: faithful m201 8-phase port ----
// BK=64, 2 LDS dbufs (128KB). 4 phases per K-tile, 16 MFMA each
// ({mt-half} x {K-half}); per phase: 4-8 asm ds_read_b128 + one 16KB
// staging quantum (2 gll16) into the OTHER dbuf + double barriers +
// lgkmcnt(0)+sched_barrier (rule 18) + setprio around the MFMA cluster.
// Counted vmcnt(4) at P2-end and P4-end: induction — at each vmcnt(4)
// point exactly the 2 newest quanta (4 loads) remain in flight; the
// quantum consumed next is always >=2 quanta old (stage lead ~3 phases).
// Stage order per tile t -> quanta of t+1: A-k0, B-k0, A-k1, B-k1,
// matching t+1's consumption order. K-half-major LDS layout
// [dbuf][A/B][kh][256 rows x 32k] keeps gll16 dests contiguous; chunk-XOR
// swizzle (c ^ (row>>1)&3 on 16B chunks in 64B rows) is conflict-free at
// octet granularity (all 8 quads covered per 8-lane group).
// MODE 0: out fp16 = acc * sb[b*DIM+col] * 0.125 * log2e  (Q proj)
// MODE 1: out fp32 = acc + sb[col]                        (out proj + bias)
#define MF(X, Y, C)                                                          \
  __builtin_amdgcn_mfma_f32_16x16x32_f16(__builtin_bit_cast(half8, (X)),     \
                                         __builtin_bit_cast(half8, (Y)),     \
                                         (C), 0, 0, 0)
#define MFROW(AI, FA)                                                        \
  acc[AI][0] = MF(FA, fb[0], acc[AI][0]);                                    \
  acc[AI][1] = MF(FA, fb[1], acc[AI][1]);                                    \
  acc[AI][2] = MF(FA, fb[2], acc[AI][2]);                                    \
  acc[AI][3] = MF(FA, fb[3], acc[AI][3]);

#define STG(GP, DB, MAT, H, TT)                                              \
  do {                                                                       \
    gll16((GP) + (TT) * 64 + (H) * 32,                                       \
          shp + (DB) * 32768 + (MAT) * 16384 + (H) * 8192 + wofs);           \
    gll16((GP) + 131072 + (TT) * 64 + (H) * 32,                              \
          shp + (DB) * 32768 + (MAT) * 16384 + (H) * 8192 + 4096 + wofs);    \
  } while (0)

#define TILE(T, AL, BL, XD, STEN, VM2Z, P4VM)                                \
  {                                                                          \
    i32x4 fa[4], fb[4];                                                      \
    /* ---- P1: B-k0 + A[mt0-3]-k0, stage A-k0(t+1) ---- */                  \
    DSR128(fb[0], BL, 32768); DSR128(fb[1], BL, 33792);                      \
    DSR128(fb[2], BL, 34816); DSR128(fb[3], BL, 35840);                      \
    DSR128(fa[0], AL, 0);     DSR128(fa[1], AL, 1024);                       \
    DSR128(fa[2], AL, 2048);  DSR128(fa[3], AL, 3072);                       \
    if (STEN) { STG(Agp, XD, 0, 0, (T) + 1); }                               \
    BARR; LGKM0;                                                             \
    __builtin_amdgcn_s_setprio(1);                                           \
    MFROW(0, fa[0]) MFROW(1, fa[1]) MFROW(2, fa[2]) MFROW(3, fa[3])          \
    __builtin_amdgcn_s_setprio(0);                                           \
    BARR;                                                                    \
    /* ---- P2: A[mt4-7]-k0, stage B-k0(t+1) ---- */                         \
    DSR128(fa[0], AL, 4096);  DSR128(fa[1], AL, 5120);                       \
    DSR128(fa[2], AL, 6144);  DSR128(fa[3], AL, 7168);                       \
    if (STEN) { STG(Bgp, XD, 1, 0, (T) + 1); }                               \
    BARR; LGKM0;                                                             \
    __builtin_amdgcn_s_setprio(1);                                           \
    MFROW(4, fa[0]) MFROW(5, fa[1]) MFROW(6, fa[2]) MFROW(7, fa[3])          \
    __builtin_amdgcn_s_setprio(0);                                           \
    if (VM2Z) { VMC(0); } else { VMC(4); }                                   \
    BARR;                                                                    \
    /* ---- P3: B-k1 + A[mt0-3]-k1, stage A-k1(t+1) ---- */                  \
    DSR128(fb[0], BL, 49152); DSR128(fb[1], BL, 50176);                      \
    DSR128(fb[2], BL, 51200); DSR128(fb[3], BL, 52224);                      \
    DSR128(fa[0], AL, 16384); DSR128(fa[1], AL, 17408);                      \
    DSR128(fa[2], AL, 18432); DSR128(fa[3], AL, 19456);                      \
    if (STEN) { STG(Agp, XD, 0, 1, (T) + 1); }                               \
    BARR; LGKM0;                                                             \
    __builtin_amdgcn_s_setprio(1);                                           \
    MFROW(0, fa[0]) MFROW(1, fa[1]) MFROW(2, fa[2]) MFROW(3, fa[3])          \
    __builtin_amdgcn_s_setprio(0);                                           \
    BARR;                                                                    \
    /* ---- P4: A[mt4-7]-k1, stage B-k1(t+1) ---- */                         \
    DSR128(fa[0], AL, 20480); DSR128(fa[1], AL, 21504);                      \
    DSR128(fa[2], AL, 22528); DSR128(fa[3], AL, 23552);                      \
    if (STEN) { STG(Bgp, XD, 1, 1, (T) + 1); }                               \
    BARR; LGKM0;                                                             \
    __builtin_amdgcn_s_setprio(1);                                           \
    MFROW(4, fa[0]) MFROW(5, fa[1]) MFROW(6, fa[2]) MFROW(7, fa[3])          \
    __builtin_amdgcn_s_setprio(0);                                           \
    if (P4VM) { VMC(4); }                                                    \
    BARR;                                                                    \
  }

template <int MODE>
__global__ __launch_bounds__(512, 2) void k_gemm(const _Float16* __restrict__ A,
                                                 const _Float16* __restrict__ Bw,
                                                 void* __restrict__ Cout,
                                                 const float* __restrict__ sb) {
  __shared__ _Float16 sh[65536];  // [dbuf2][A/B][kh2][256 rows x 32 k]
  const int tid = threadIdx.x;
  const int w = tid >> 6, l = tid & 63;
  const int q4 = l >> 4, mm = l & 15;
  const int wm = w & 1, wn = w >> 1;
  // bijective XCD swizzle (256 wgs, 8 XCDs): each XCD gets 32 consecutive
  // tiles sharing one 512KB B-panel (L2-resident).
  const int lin = blockIdx.y * 64 + blockIdx.x;
  const int sw = (lin & 7) * 32 + (lin >> 3);
  const int m0 = (sw & 63) * 256, n0 = (sw >> 6) * 256;
  f32x4 acc[8][4] = {};

  // staging: quantum = 16KB (256 rows x 32k, 64B rows); per gll16 lane l:
  // row = base + (l>>2), stored chunk c = l&3, fetched global chunk
  // c ^ ((row>>1)&3) = (l&3) ^ ((l>>3)&3).
  const int sch8 = ((l & 3) ^ ((l >> 3) & 3)) * 8;
  const _Float16* Agp = A + (size_t)(m0 + w * 16 + (l >> 2)) * DIM + sch8;
  const _Float16* Bgp = Bw + (size_t)(n0 + w * 16 + (l >> 2)) * DIM + sch8;
  _Float16* shp = sh;
  const int wofs = w * 512;

  // reader: frag row r, global chunk q4 stored at q4 ^ ((r>>1)&3) =
  // q4 ^ ((mm>>1)&3) (row bases are multiples of 16).
  const int sw16 = (q4 ^ ((mm >> 1) & 3)) * 16;
  const unsigned shb = lds_addr(sh);
  const unsigned aL0 = shb + (unsigned)((wm * 128 + mm) * 64 + sw16);
  const unsigned aL1 = aL0 + 65536u;
  const unsigned bL0 = shb + (unsigned)((wn * 64 + mm) * 64 + sw16);
  const unsigned bL1 = bL0 + 65536u;

  // prologue: stage all 4 quanta of tile 0 into dbuf 0; drain; barrier.
  STG(Agp, 0, 0, 0, -1 + 1);  // A-k0(0)  (TT=0)
  STG(Bgp, 0, 1, 0, 0);
  STG(Agp, 0, 0, 1, 0);
  STG(Bgp, 0, 1, 1, 0);
  VMC(0);
  BARR;

  for (int tp = 0; tp < 8; tp++) {
    TILE(2 * tp, aL0, bL0, 1, 1, 0, 1);
    const int st = (tp < 7);
    TILE(2 * tp + 1, aL1, bL1, 0, st, !st, st);
  }

  if (MODE == 0) {
    _Float16* Lh = (_Float16*)sh;  // [64][264] fp16 per phase (padded)
    const float lsc = 0.125f * 1.44269504088896f;
    #pragma unroll
    for (int p = 0; p < 4; p++) {
      if (wm == (p >> 1)) {
        #pragma unroll
        for (int nt = 0; nt < 4; nt++) {
          const int cl = wn * 64 + nt * 16 + mm;
          const float s = sb[(m0 >> 12) * DIM + n0 + cl] * lsc;
          #pragma unroll
          for (int mtl = 0; mtl < 4; mtl++) {
            const int mt = (p & 1) * 4 + mtl;
            const int rl = mtl * 16 + q4 * 4;
            #pragma unroll
            for (int r = 0; r < 4; r++)
              Lh[(rl + r) * 264 + cl] = (_Float16)(acc[mt][nt][r] * s);
          }
        }
      }
      __syncthreads();
      const int row_l = tid >> 3, c0 = (tid & 7) * 32;
      _Float16* dst = (_Float16*)Cout + (size_t)(m0 + p * 64 + row_l) * DIM + n0 + c0;
      #pragma unroll
      for (int i = 0; i < 4; i++)
        *(half8*)(dst + i * 8) = *(half8*)(Lh + row_l * 264 + c0 + i * 8);
      __syncthreads();
    }
  } else {
    float* Lf = (float*)sh;  // [32][260] f32 per phase (padded)
    #pragma unroll
    for (int p = 0; p < 8; p++) {
      if (wm == (p >> 2)) {
        #pragma unroll
        for (int nt = 0; nt < 4; nt++) {
          const int cl = wn * 64 + nt * 16 + mm;
          const float s = sb[n0 + cl];
          #pragma unroll
          for (int mtl = 0; mtl < 2; mtl++) {
            const int mt = (p & 3) * 2 + mtl;
            const int rl = mtl * 16 + q4 * 4;
            #pragma unroll
            for (int r = 0; r < 4; r++)
              Lf[(rl + r) * 260 + cl] = acc[mt][nt][r] + s;
          }
        }
      }
      __syncthreads();
      const int row_l = tid >> 4, c0 = (tid & 15) * 16;
      float* dst = (float*)Cout + (size_t)(m0 + p * 32 + row_l) * DIM + n0 + c0;
      #pragma unroll
      for (int i = 0; i < 4; i++)
        *(f32x4*)(dst + i * 4) = *(f32x4*)(Lf + row_l * 260 + c0 + i * 4);
      __syncthreads();
    }
  }
}

// ---- fused attention v4: grid (8,64)=512 blocks, 8 tiles/wave ----
__global__ __launch_bounds__(256) void k_attn(const _Float16* __restrict__ Q,
                                              const _Float16* __restrict__ E,
                                              const _Float16* __restrict__ Ftp,
                                              const float* __restrict__ Sv,
                                              _Float16* __restrict__ O) {
  __shared__ _Float16 Ps[4][16][264];
  const int tid = threadIdx.x;
  const int w = tid >> 6, lane = tid & 63;
  const int q4 = lane >> 4, mm = lane & 15;
  const int bh = blockIdx.y;
  const int b = bh >> 4, h = bh & 15;
  const int row_base = blockIdx.x * 512 + w * 128;  // 8 tiles of 16 rows

  half8 ef[16][2];
  #pragma unroll
  for (int t = 0; t < 16; t++)
    #pragma unroll
    for (int kk = 0; kk < 2; kk++)
      ef[t][kk] = *(const half8*)(E + (t * 16 + mm) * HD + kk * 32 + q4 * 8);
  half8 ff[4][8];
  #pragma unroll
  for (int nt = 0; nt < 4; nt++)
    #pragma unroll
    for (int kk = 0; kk < 8; kk++)
      ff[nt][kk] = *(const half8*)(Ftp + (nt * 16 + mm) * KP + kk * 32 + q4 * 8);
  float sv[4];
  #pragma unroll
  for (int nt = 0; nt < 4; nt++) sv[nt] = Sv[b * DIM + h * HD + nt * 16 + mm];

  const _Float16* Qbase = Q + ((size_t)(b * SEQ + row_base + mm)) * DIM + h * HD + q4 * 8;
  half8 qa0 = *(const half8*)(Qbase);
  half8 qa1 = *(const half8*)(Qbase + 32);

  for (int tile = 0; tile < 8; tile++) {
    f32x4 acc[16] = {};
    #pragma unroll
    for (int t = 0; t < 16; t++)
      acc[t] = __builtin_amdgcn_mfma_f32_16x16x32_f16(qa0, ef[t][0], acc[t], 0, 0, 0);
    #pragma unroll
    for (int t = 0; t < 16; t++)
      acc[t] = __builtin_amdgcn_mfma_f32_16x16x32_f16(qa1, ef[t][1], acc[t], 0, 0, 0);
    half8 qn0, qn1;
    if (tile < 7) {
      const _Float16* Qn = Qbase + (size_t)(tile + 1) * 16 * DIM;
      qn0 = *(const half8*)(Qn);
      qn1 = *(const half8*)(Qn + 32);
    }
    float mx[4] = {-1e30f, -1e30f, -1e30f, -1e30f};
    #pragma unroll
    for (int t = 0; t < 16; t++)
      #pragma unroll
      for (int r = 0; r < 4; r++) mx[r] = fmaxf(mx[r], acc[t][r]);
    #pragma unroll
    for (int r = 0; r < 4; r++) {
      float m = mx[r];
      m = fmaxf(m, DPPF(m, 0x121));
      m = fmaxf(m, DPPF(m, 0x122));
      m = fmaxf(m, DPPF(m, 0x124));
      m = fmaxf(m, DPPF(m, 0x128));
      mx[r] = m;
    }
    float sm[4] = {0.f, 0.f, 0.f, 0.f};
    #pragma unroll
    for (int t = 0; t < 16; t++)
      #pragma unroll
      for (int r = 0; r < 4; r++) {
        float p = __builtin_amdgcn_exp2f(acc[t][r] - mx[r]);
        acc[t][r] = p;
        sm[r] += p;
      }
    #pragma unroll
    for (int r = 0; r < 4; r++) {
      float s = sm[r];
      s += DPPF(s, 0x121);
      s += DPPF(s, 0x122);
      s += DPPF(s, 0x124);
      s += DPPF(s, 0x128);
      sm[r] = 1.f / s;
    }
    #pragma unroll
    for (int r = 0; r < 4; r++) {
      half8 h0, h1;
      #pragma unroll
      for (int t = 0; t < 8; t++) h0[t] = (_Float16)acc[t][r];
      #pragma unroll
      for (int t = 0; t < 8; t++) h1[t] = (_Float16)acc[t + 8][r];
      *(half8*)&Ps[w][q4 * 4 + r][mm * 16] = h0;
      *(half8*)&Ps[w][q4 * 4 + r][mm * 16 + 8] = h1;
    }
    f32x4 acc2[4] = {};
    #pragma unroll
    for (int kk = 0; kk < 8; kk++) {
      half8 pa = *(const half8*)&Ps[w][mm][kk * 32 + q4 * 8];
      #pragma unroll
      for (int nt = 0; nt < 4; nt++)
        acc2[nt] = __builtin_amdgcn_mfma_f32_16x16x32_f16(pa, ff[nt][kk], acc2[nt], 0, 0, 0);
    }
    const int rw0 = row_base + tile * 16;
    #pragma unroll
    for (int nt = 0; nt < 4; nt++)
      #pragma unroll
      for (int r = 0; r < 4; r++)
        O[(size_t)(b * SEQ + rw0 + q4 * 4 + r) * DIM + h * HD + nt * 16 + mm] =
            (_Float16)(acc2[nt][r] * (sm[r] * sv[nt]));
    qa0 = qn0;
    qa1 = qn1;
  }
}

extern "C" void kernel_launch(void* const* d_in, const int* in_sizes, int n_in,
                              void* d_out, int out_size, void* d_ws, size_t ws_size,
                              hipStream_t stream) {
  (void)in_sizes; (void)n_in; (void)out_size; (void)ws_size;
  const float* x  = (const float*)d_in[0];
  const float* Wq = (const float*)d_in[1];
  const float* Wk = (const float*)d_in[2];
  const float* Wv = (const float*)d_in[3];
  const float* E  = (const float*)d_in[4];
  const float* F  = (const float*)d_in[5];
  const float* Wo = (const float*)d_in[6];
  const float* bo = (const float*)d_in[7];
  char* ws = (char*)d_ws;
  _Float16* x_h  = (_Float16*)(ws);
  _Float16* O_h  = (_Float16*)(ws);          // aliases x_h (dead after Q GEMM)
  _Float16* Q_h  = (_Float16*)(ws + 33554432);
  _Float16* Wq_h = (_Float16*)(ws + 67108864);
  _Float16* Wo_h = (_Float16*)(ws + 69206016);
  _Float16* E_h  = (_Float16*)(ws + 71303168);
  _Float16* Ft_h = (_Float16*)(ws + 71335936);
  float* xsum    = (float*)(ws + 71368704);
  float* Sk      = (float*)(ws + 71385088);
  float* Sv      = (float*)(ws + 71401472);
  float* out     = (float*)d_out;

  k_cvt<<<8192, 256, 0, stream>>>(x, x_h);
  k_misc<<<88, 256, 0, stream>>>(E, F, E_h, Ft_h, xsum);
  k_cvtw<<<1024, 256, 0, stream>>>(Wq, Wo, Wq_h, Wo_h);
  k_xsum<<<dim3(4, BATCH, 32), 256, 0, stream>>>(x_h, xsum);
  k_sksv<<<2048, 256, 0, stream>>>(xsum, Wk, Wv, Sk, Sv);
  k_gemm<0><<<dim3(64, 4), 512, 0, stream>>>(x_h, Wq_h, (void*)Q_h, Sk);
  k_attn<<<dim3(8, 64), 256, 0, stream>>>(Q_h, E_h, Ft_h, Sv, O_h);
  k_gemm<1><<<dim3(64, 4), 512, 0, stream>>>(O_h, Wo_h, (void*)out, bo);
}

// Round 6
// 301.407 us; speedup vs baseline: 1.0238x; 1.0238x over previous
//
#include <hip/hip_runtime.h>

#define DIM 1024
#define BATCH 4
#define SEQ 4096
#define NH 16
#define HD 64
#define KP 256

typedef float f32x4 __attribute__((ext_vector_type(4)));
typedef _Float16 half8 __attribute__((ext_vector_type(8)));

// DPP row_ror:n within 16-lane rows. ctrl = 0x120|n.
#define DPPF(v, ctrl)                                                        \
  __builtin_bit_cast(float, __builtin_amdgcn_mov_dpp(                        \
                                __builtin_bit_cast(int, v), ctrl, 0xF, 0xF, true))

// ---- fp32 -> fp16 elementwise convert, 8 elems/thread ----
__global__ void k_cvt(const float* __restrict__ s, _Float16* __restrict__ d) {
  int i = (blockIdx.x * 256 + threadIdx.x) * 8;
  f32x4 a = *(const f32x4*)(s + i);
  f32x4 b = *(const f32x4*)(s + i + 4);
  half8 h;
  h[0] = a[0]; h[1] = a[1]; h[2] = a[2]; h[3] = a[3];
  h[4] = b[0]; h[5] = b[1]; h[6] = b[2]; h[7] = b[3];
  *(half8*)(d + i) = h;
}

// Wq and Wo converts merged: grid 1024 blocks
__global__ void k_cvtw(const float* __restrict__ Wq, const float* __restrict__ Wo,
                       _Float16* __restrict__ Wq_h, _Float16* __restrict__ Wo_h) {
  int bb = blockIdx.x;
  const float* s = (bb < 512) ? Wq : Wo;
  _Float16* d = (bb < 512) ? Wq_h : Wo_h;
  int i = ((bb & 511) * 256 + threadIdx.x) * 8;
  f32x4 a = *(const f32x4*)(s + i);
  f32x4 b = *(const f32x4*)(s + i + 4);
  half8 h;
  h[0] = a[0]; h[1] = a[1]; h[2] = a[2]; h[3] = a[3];
  h[4] = b[0]; h[5] = b[1]; h[6] = b[2]; h[7] = b[3];
  *(half8*)(d + i) = h;
}

// misc small work merged: grid 88 blocks
__global__ void k_misc(const float* __restrict__ E, const float* __restrict__ F,
                       _Float16* __restrict__ E_h, _Float16* __restrict__ Ft,
                       float* __restrict__ xsum) {
  int bb = blockIdx.x;
  if (bb < 16) {
    xsum[bb * 256 + threadIdx.x] = 0.f;
  } else if (bb < 24) {
    int i = ((bb - 16) * 256 + threadIdx.x) * 8;
    f32x4 a = *(const f32x4*)(E + i);
    f32x4 b = *(const f32x4*)(E + i + 4);
    half8 h;
    h[0] = a[0]; h[1] = a[1]; h[2] = a[2]; h[3] = a[3];
    h[4] = b[0]; h[5] = b[1]; h[6] = b[2]; h[7] = b[3];
    *(half8*)(E_h + i) = h;
  } else {
    int i = (bb - 24) * 256 + threadIdx.x;  // 16384
    int k = i >> 6, d = i & 63;
    Ft[d * KP + (k & 15) * 16 + (k >> 4)] = (_Float16)F[i];
  }
}

// xsum[b,c] = sum_n x[b,n,c]; reads fp16 x_h; grid (4,B,32)
__global__ void k_xsum(const _Float16* __restrict__ xh, float* __restrict__ xs) {
  int c = blockIdx.x * 256 + threadIdx.x;
  int b = blockIdx.y;
  int n0 = blockIdx.z * 128;
  const _Float16* p = xh + (size_t)(b * SEQ + n0) * DIM + c;
  float s = 0.f;
  #pragma unroll 8
  for (int i = 0; i < 128; i++) s += (float)p[i * DIM];
  atomicAdd(&xs[b * DIM + c], s);
}

// Sk[b,c] = xsum[b,:]@Wk[c,:], Sv likewise. One wave per output dot.
__global__ void k_sksv(const float* __restrict__ xs, const float* __restrict__ Wk,
                       const float* __restrict__ Wv, float* __restrict__ Sk,
                       float* __restrict__ Sv) {
  int idx = blockIdx.x * 4 + (threadIdx.x >> 6);
  int lane = threadIdx.x & 63;
  int kv = idx >> 12;
  int rem = idx & 4095;
  int b = rem >> 10, c = rem & 1023;
  const float* W = (kv ? Wv : Wk) + c * DIM;
  const float* xp = xs + b * DIM;
  float a = 0.f;
  #pragma unroll
  for (int i = 0; i < 16; i++) a += xp[lane + i * 64] * W[lane + i * 64];
  for (int off = 32; off; off >>= 1) a += __shfl_down(a, off);
  if (lane == 0) (kv ? Sv : Sk)[rem] = a;
}

// ---- fp16 MFMA GEMM, round 8: reg-staged (T14), no global_load_lds ----
// Rounds 0-5 postmortem: five schedule variants all plateau ~3300 cyc/tile
// (floor 1280) with the ONE shared element being global_load_lds; its
// return path writes LDS through the DS unit (16B/lane granularity) and is
// the prime suspect for the residual ~2000 cyc/tile. This round isolates
// that variable: stage via global_load_dwordx4 -> VGPR at tile start, then
// ds_write_b128 AFTER the MFMA block (T14 split: HBM latency hides under
// the ~1280-cyc MFMA region). Dbuf-2 (64KB LDS), ONE __syncthreads/tile:
//   tile t: issue glb loads(t+1) | frag ds_reads(buf t&1) | 32 MFMA |
//           sched_barrier | ds_write(t+1 -> buf (t+1)&1) | __syncthreads
// WAR-safe: tile t-1's frag reads complete before its own barrier (reads
// feed that tile's MFMAs). No vmem->LDS writes exist, so the compiler
// alias-drain hazard of rounds 0-4 is structurally gone. Write-side chunk
// XOR swizzle mirrors the proven conflict-free read pattern. Natural grid
// (64,4): lin%8 = m%8, so the 4 n-blocks of each A-panel share one XCD's
// L2 (round-5's remap broke this; FETCH 24.6 -> 67.7 MB).
// MODE 0: out fp16 = acc * sb[b*DIM+col] * 0.125 * log2e  (Q proj)
// MODE 1: out fp32 = acc + sb[col]                        (out proj + bias)
template <int MODE>
__global__ __launch_bounds__(512, 2) void k_gemm(const _Float16* __restrict__ A,
                                                 const _Float16* __restrict__ Bw,
                                                 void* __restrict__ Cout,
                                                 const float* __restrict__ sb) {
  __shared__ _Float16 sh[2][2][8192];  // [dbuf][A=0/B=1][256 rows x 32 k]
  const int tid = threadIdx.x;
  const int w = tid >> 6, l = tid & 63;
  const int q4 = l >> 4, mm = l & 15;
  const int wm = w & 1, wn = w >> 1;
  const int m0 = blockIdx.x * 256, n0 = blockIdx.y * 256;
  f32x4 acc[8][4] = {};

  // staging: thread covers rows rowl and rowl+16, natural global chunk
  // (l&3); LDS write chunk = (l&3) ^ ((l>>3)&3)  (row-key XOR, so
  // LDS[row][c] = global[row][c ^ ((row>>1)&3)], same layout as before).
  const int rowl = w * 32 + (l >> 2);
  const _Float16* Ag = A + (size_t)(m0 + rowl) * DIM + (l & 3) * 8;
  const _Float16* Bg = Bw + (size_t)(n0 + rowl) * DIM + (l & 3) * 8;
  const int wofs = rowl * 32 + ((l & 3) ^ ((l >> 3) & 3)) * 8;
  // reader: global chunk q4 of row r stored at chunk q4 ^ ((r>>1)&3);
  // (r>>1)&3 == (mm>>1)&3 for all frag rows.
  const int csw = (q4 ^ ((mm >> 1) & 3)) * 8;
  const int rdo_a = (wm * 128 + mm) * 32 + csw;
  const int rdo_b = (wn * 64 + mm) * 32 + csw;

  half8 ra0, ra1, rb0, rb1;
  // prologue: tile 0 -> regs -> buf0
  ra0 = *(const half8*)(Ag);
  ra1 = *(const half8*)(Ag + 16 * DIM);
  rb0 = *(const half8*)(Bg);
  rb1 = *(const half8*)(Bg + 16 * DIM);
  *(half8*)&sh[0][0][wofs] = ra0;
  *(half8*)&sh[0][0][wofs + 512] = ra1;
  *(half8*)&sh[0][1][wofs] = rb0;
  *(half8*)&sh[0][1][wofs + 512] = rb1;
  __syncthreads();

  #pragma unroll 2
  for (int t = 0; t < 32; t++) {
    const int cur = t & 1;
    if (t < 31) {  // issue next-tile loads first: latency hides under MFMA
      const int kn = (t + 1) * 32;
      ra0 = *(const half8*)(Ag + kn);
      ra1 = *(const half8*)(Ag + kn + 16 * DIM);
      rb0 = *(const half8*)(Bg + kn);
      rb1 = *(const half8*)(Bg + kn + 16 * DIM);
    }
    half8 av[8], bv[4];
    const _Float16* Ap = &sh[cur][0][rdo_a];
    const _Float16* Bp = &sh[cur][1][rdo_b];
    #pragma unroll
    for (int i = 0; i < 4; i++) bv[i] = *(const half8*)(Bp + i * 512);
    #pragma unroll
    for (int i = 0; i < 8; i++) av[i] = *(const half8*)(Ap + i * 512);
    __builtin_amdgcn_s_setprio(1);
    #pragma unroll
    for (int mt = 0; mt < 8; mt++)
      #pragma unroll
      for (int nt = 0; nt < 4; nt++)
        acc[mt][nt] = __builtin_amdgcn_mfma_f32_16x16x32_f16(av[mt], bv[nt], acc[mt][nt], 0, 0, 0);
    __builtin_amdgcn_s_setprio(0);
    __builtin_amdgcn_sched_barrier(0);  // keep ds_writes (vmcnt wait) below MFMA
    if (t < 31) {
      _Float16* dA = &sh[cur ^ 1][0][wofs];
      _Float16* dB = &sh[cur ^ 1][1][wofs];
      *(half8*)dA = ra0;
      *(half8*)(dA + 512) = ra1;
      *(half8*)dB = rb0;
      *(half8*)(dB + 512) = rb1;
    }
    __syncthreads();
  }

  if (MODE == 0) {
    _Float16* Lh = (_Float16*)sh;  // [64][264] fp16 per phase (padded)
    const float lsc = 0.125f * 1.44269504088896f;
    #pragma unroll
    for (int p = 0; p < 4; p++) {
      if (wm == (p >> 1)) {
        #pragma unroll
        for (int nt = 0; nt < 4; nt++) {
          const int cl = wn * 64 + nt * 16 + mm;
          const float s = sb[(m0 >> 12) * DIM + n0 + cl] * lsc;
          #pragma unroll
          for (int mtl = 0; mtl < 4; mtl++) {
            const int mt = (p & 1) * 4 + mtl;
            const int rl = mtl * 16 + q4 * 4;
            #pragma unroll
            for (int r = 0; r < 4; r++)
              Lh[(rl + r) * 264 + cl] = (_Float16)(acc[mt][nt][r] * s);
          }
        }
      }
      __syncthreads();
      const int row_l = tid >> 3, c0 = (tid & 7) * 32;
      _Float16* dst = (_Float16*)Cout + (size_t)(m0 + p * 64 + row_l) * DIM + n0 + c0;
      #pragma unroll
      for (int i = 0; i < 4; i++)
        *(half8*)(dst + i * 8) = *(half8*)(Lh + row_l * 264 + c0 + i * 8);
      __syncthreads();
    }
  } else {
    float* Lf = (float*)sh;  // [32][260] f32 per phase (padded)
    #pragma unroll
    for (int p = 0; p < 8; p++) {
      if (wm == (p >> 2)) {
        #pragma unroll
        for (int nt = 0; nt < 4; nt++) {
          const int cl = wn * 64 + nt * 16 + mm;
          const float s = sb[n0 + cl];
          #pragma unroll
          for (int mtl = 0; mtl < 2; mtl++) {
            const int mt = (p & 3) * 2 + mtl;
            const int rl = mtl * 16 + q4 * 4;
            #pragma unroll
            for (int r = 0; r < 4; r++)
              Lf[(rl + r) * 260 + cl] = acc[mt][nt][r] + s;
          }
        }
      }
      __syncthreads();
      const int row_l = tid >> 4, c0 = (tid & 15) * 16;
      float* dst = (float*)Cout + (size_t)(m0 + p * 32 + row_l) * DIM + n0 + c0;
      #pragma unroll
      for (int i = 0; i < 4; i++)
        *(f32x4*)(dst + i * 4) = *(f32x4*)(Lf + row_l * 260 + c0 + i * 4);
      __syncthreads();
    }
  }
}

// ---- fused attention v4: grid (8,64)=512 blocks, 8 tiles/wave ----
__global__ __launch_bounds__(256) void k_attn(const _Float16* __restrict__ Q,
                                              const _Float16* __restrict__ E,
                                              const _Float16* __restrict__ Ftp,
                                              const float* __restrict__ Sv,
                                              _Float16* __restrict__ O) {
  __shared__ _Float16 Ps[4][16][264];
  const int tid = threadIdx.x;
  const int w = tid >> 6, lane = tid & 63;
  const int q4 = lane >> 4, mm = lane & 15;
  const int bh = blockIdx.y;
  const int b = bh >> 4, h = bh & 15;
  const int row_base = blockIdx.x * 512 + w * 128;  // 8 tiles of 16 rows

  half8 ef[16][2];
  #pragma unroll
  for (int t = 0; t < 16; t++)
    #pragma unroll
    for (int kk = 0; kk < 2; kk++)
      ef[t][kk] = *(const half8*)(E + (t * 16 + mm) * HD + kk * 32 + q4 * 8);
  half8 ff[4][8];
  #pragma unroll
  for (int nt = 0; nt < 4; nt++)
    #pragma unroll
    for (int kk = 0; kk < 8; kk++)
      ff[nt][kk] = *(const half8*)(Ftp + (nt * 16 + mm) * KP + kk * 32 + q4 * 8);
  float sv[4];
  #pragma unroll
  for (int nt = 0; nt < 4; nt++) sv[nt] = Sv[b * DIM + h * HD + nt * 16 + mm];

  const _Float16* Qbase = Q + ((size_t)(b * SEQ + row_base + mm)) * DIM + h * HD + q4 * 8;
  half8 qa0 = *(const half8*)(Qbase);
  half8 qa1 = *(const half8*)(Qbase + 32);

  for (int tile = 0; tile < 8; tile++) {
    f32x4 acc[16] = {};
    #pragma unroll
    for (int t = 0; t < 16; t++)
      acc[t] = __builtin_amdgcn_mfma_f32_16x16x32_f16(qa0, ef[t][0], acc[t], 0, 0, 0);
    #pragma unroll
    for (int t = 0; t < 16; t++)
      acc[t] = __builtin_amdgcn_mfma_f32_16x16x32_f16(qa1, ef[t][1], acc[t], 0, 0, 0);
    half8 qn0, qn1;
    if (tile < 7) {
      const _Float16* Qn = Qbase + (size_t)(tile + 1) * 16 * DIM;
      qn0 = *(const half8*)(Qn);
      qn1 = *(const half8*)(Qn + 32);
    }
    float mx[4] = {-1e30f, -1e30f, -1e30f, -1e30f};
    #pragma unroll
    for (int t = 0; t < 16; t++)
      #pragma unroll
      for (int r = 0; r < 4; r++) mx[r] = fmaxf(mx[r], acc[t][r]);
    #pragma unroll
    for (int r = 0; r < 4; r++) {
      float m = mx[r];
      m = fmaxf(m, DPPF(m, 0x121));
      m = fmaxf(m, DPPF(m, 0x122));
      m = fmaxf(m, DPPF(m, 0x124));
      m = fmaxf(m, DPPF(m, 0x128));
      mx[r] = m;
    }
    float sm[4] = {0.f, 0.f, 0.f, 0.f};
    #pragma unroll
    for (int t = 0; t < 16; t++)
      #pragma unroll
      for (int r = 0; r < 4; r++) {
        float p = __builtin_amdgcn_exp2f(acc[t][r] - mx[r]);
        acc[t][r] = p;
        sm[r] += p;
      }
    #pragma unroll
    for (int r = 0; r < 4; r++) {
      float s = sm[r];
      s += DPPF(s, 0x121);
      s += DPPF(s, 0x122);
      s += DPPF(s, 0x124);
      s += DPPF(s, 0x128);
      sm[r] = 1.f / s;
    }
    #pragma unroll
    for (int r = 0; r < 4; r++) {
      half8 h0, h1;
      #pragma unroll
      for (int t = 0; t < 8; t++) h0[t] = (_Float16)acc[t][r];
      #pragma unroll
      for (int t = 0; t < 8; t++) h1[t] = (_Float16)acc[t + 8][r];
      *(half8*)&Ps[w][q4 * 4 + r][mm * 16] = h0;
      *(half8*)&Ps[w][q4 * 4 + r][mm * 16 + 8] = h1;
    }
    f32x4 acc2[4] = {};
    #pragma unroll
    for (int kk = 0; kk < 8; kk++) {
      half8 pa = *(const half8*)&Ps[w][mm][kk * 32 + q4 * 8];
      #pragma unroll
      for (int nt = 0; nt < 4; nt++)
        acc2[nt] = __builtin_amdgcn_mfma_f32_16x16x32_f16(pa, ff[nt][kk], acc2[nt], 0, 0, 0);
    }
    const int rw0 = row_base + tile * 16;
    #pragma unroll
    for (int nt = 0; nt < 4; nt++)
      #pragma unroll
      for (int r = 0; r < 4; r++)
        O[(size_t)(b * SEQ + rw0 + q4 * 4 + r) * DIM + h * HD + nt * 16 + mm] =
            (_Float16)(acc2[nt][r] * (sm[r] * sv[nt]));
    qa0 = qn0;
    qa1 = qn1;
  }
}

extern "C" void kernel_launch(void* const* d_in, const int* in_sizes, int n_in,
                              void* d_out, int out_size, void* d_ws, size_t ws_size,
                              hipStream_t stream) {
  (void)in_sizes; (void)n_in; (void)out_size; (void)ws_size;
  const float* x  = (const float*)d_in[0];
  const float* Wq = (const float*)d_in[1];
  const float* Wk = (const float*)d_in[2];
  const float* Wv = (const float*)d_in[3];
  const float* E  = (const float*)d_in[4];
  const float* F  = (const float*)d_in[5];
  const float* Wo = (const float*)d_in[6];
  const float* bo = (const float*)d_in[7];
  char* ws = (char*)d_ws;
  _Float16* x_h  = (_Float16*)(ws);
  _Float16* O_h  = (_Float16*)(ws);          // aliases x_h (dead after Q GEMM)
  _Float16* Q_h  = (_Float16*)(ws + 33554432);
  _Float16* Wq_h = (_Float16*)(ws + 67108864);
  _Float16* Wo_h = (_Float16*)(ws + 69206016);
  _Float16* E_h  = (_Float16*)(ws + 71303168);
  _Float16* Ft_h = (_Float16*)(ws + 71335936);
  float* xsum    = (float*)(ws + 71368704);
  float* Sk      = (float*)(ws + 71385088);
  float* Sv      = (float*)(ws + 71401472);
  float* out     = (float*)d_out;

  k_cvt<<<8192, 256, 0, stream>>>(x, x_h);
  k_misc<<<88, 256, 0, stream>>>(E, F, E_h, Ft_h, xsum);
  k_cvtw<<<1024, 256, 0, stream>>>(Wq, Wo, Wq_h, Wo_h);
  k_xsum<<<dim3(4, BATCH, 32), 256, 0, stream>>>(x_h, xsum);
  k_sksv<<<2048, 256, 0, stream>>>(xsum, Wk, Wv, Sk, Sv);
  k_gemm<0><<<dim3(64, 4), 512, 0, stream>>>(x_h, Wq_h, (void*)Q_h, Sk);
  k_attn<<<dim3(8, 64), 256, 0, stream>>>(Q_h, E_h, Ft_h, Sv, O_h);
  k_gemm<1><<<dim3(64, 4), 512, 0, stream>>>(O_h, Wo_h, (void*)out, bo);
}